// Round 10
// baseline (3462.002 us; speedup 1.0000x reference)
//
#include <hip/hip_runtime.h>

typedef __attribute__((ext_vector_type(8))) short bf16x8;
typedef __attribute__((ext_vector_type(4))) float f32x4;
typedef __attribute__((ext_vector_type(8))) unsigned short u16x8;
typedef unsigned long long u64t;
typedef unsigned int u32t;

#define NROWS 65536
#define DDIM  256
#define KCODE 2048

__device__ __forceinline__ unsigned short f2bf_rne(float f) {
  unsigned int u = __builtin_bit_cast(unsigned int, f);
  unsigned int r = (u + 0x7fffu + ((u >> 16) & 1u)) >> 16;
  return (unsigned short)r;
}
__device__ __forceinline__ float bf2f(unsigned short h) {
  unsigned int u = ((unsigned int)h) << 16;
  return __builtin_bit_cast(float, u);
}

typedef const unsigned int __attribute__((address_space(1)))* gp1_t;
typedef unsigned int __attribute__((address_space(3)))* lp3_t;
__device__ __forceinline__ void gload_lds16(const void* g, void* l) {
  __builtin_amdgcn_global_load_lds((gp1_t)g, (lp3_t)l, 16, 0, 0);
}

__device__ __forceinline__ u64t shfl_xor_u64(u64t v, int off) {
  u32t lo = (u32t)v, hi = (u32t)(v >> 32);
  lo = __shfl_xor(lo, off);
  hi = __shfl_xor(hi, off);
  return ((u64t)hi << 32) | lo;
}

// --- prep A: x -> [hi(256)|lo(256)] bf16 per row (overlay on d_out) + ||x||^2 + key init ---
__global__ __launch_bounds__(256) void prep_A(const float* __restrict__ x,
                                              unsigned short* __restrict__ Ap,
                                              float* __restrict__ frow,
                                              u64t* __restrict__ keyArr) {
  const int t   = threadIdx.x;
  const int row = blockIdx.x * 8 + (t >> 5);
  const int d0  = (t & 31) * 8;
  const float* xr = x + (size_t)row * DDIM + d0;
  float4 v0 = *reinterpret_cast<const float4*>(xr);
  float4 v1 = *reinterpret_cast<const float4*>(xr + 4);
  float vv[8] = {v0.x, v0.y, v0.z, v0.w, v1.x, v1.y, v1.z, v1.w};
  u16x8 hi, lo;
  float ss = 0.f;
  #pragma unroll
  for (int i = 0; i < 8; ++i) {
    ss += vv[i] * vv[i];
    unsigned short h = f2bf_rne(vv[i]);
    hi[i] = h;
    lo[i] = f2bf_rne(vv[i] - bf2f(h));
  }
  char* rowp = (char*)Ap + (size_t)row * 1024;
  *reinterpret_cast<u16x8*>(rowp + d0 * 2)       = hi;
  *reinterpret_cast<u16x8*>(rowp + 512 + d0 * 2) = lo;
  #pragma unroll
  for (int off = 16; off; off >>= 1) ss += __shfl_xor(ss, off);
  if ((t & 31) == 0) { frow[row] = ss; keyArr[row] = ~0ull; }
}

// --- prep B: E[d][k] -> Bp[k][512]=[hi(256)|lo(256)] bf16 k-major; enorm; Etg[k][d] fp32 ---
__global__ __launch_bounds__(256) void prep_B(const float* __restrict__ E,
                                              unsigned short* __restrict__ Bp,
                                              float* __restrict__ enorm,
                                              float* __restrict__ Etg) {
  const int k0 = blockIdx.x;
  const int d  = threadIdx.x;
  float v = E[(size_t)d * KCODE + k0];
  Etg[(size_t)k0 * DDIM + d] = v;
  unsigned short h = f2bf_rne(v);
  unsigned short l = f2bf_rne(v - bf2f(h));
  unsigned short* col = Bp + (size_t)k0 * 512;
  col[d] = h; col[256 + d] = l;
  float s = v * v;
  #pragma unroll
  for (int off = 32; off; off >>= 1) s += __shfl_xor(s, off);
  __shared__ float wsum[4];
  if ((threadIdx.x & 63) == 0) wsum[threadIdx.x >> 6] = s;
  __syncthreads();
  if (threadIdx.x == 0) enorm[k0] = (wsum[0] + wsum[1]) + (wsum[2] + wsum[3]);
}

// --- main: distance GEMM, 8 physical K=32 chunks. Codes staged in LDS
// (2x32KB dbuf -> 2 blocks/CU); x fragments loaded per-lane direct to
// double-buffered REGISTERS (static sets, 2-chunk-unrolled). One prefetch
// batch per chunk {4 stage + 8 x loads}, one derived vmcnt(12) wait.
// Cross-block overlap (2 blocks/CU) hides reads/barriers under MFMA.
__global__ __launch_bounds__(512, 4) void vq_nn(
    const unsigned short* __restrict__ Ap,   // x packed  [row][hi|lo] 1024 B/row
    const unsigned short* __restrict__ Bp,   // codes     [k][hi|lo]   1024 B/code
    const float* __restrict__ enorm,
    const float* __restrict__ frow,
    u64t* __restrict__ keyArr)
{
  extern __shared__ __align__(16) char lds[];   // 2 x { ch 16K | cl 16K } = 64 KB

  const int tid = threadIdx.x;
  const int w   = tid >> 6;
  const int l   = tid & 63;
  const int l15 = l & 15;
  const int lg  = l >> 4;
  const int wr  = w >> 2;      // code half (0..1)
  const int wc  = w & 3;       // x-col quarter (0..3)

  // XCD-aware swizzle (FETCH 371->106MB, r7)
  const int xcd = blockIdx.x & 7;
  const int seq = blockIdx.x >> 3;
  const int cb  = seq & 7;                  // code block 0..7
  const int nb  = xcd * 32 + (seq >> 3);    // x-row block 0..255

  const int rl0  = tid >> 2;                // 0..127
  const int c16  = (tid & 3) * 16;
  const int srcS = c16 ^ (((rl0 >> 1) & 3) << 4);   // pre-swizzled source (involution)
  const char* BpB = (const char*)Bp + (size_t)cb * 256 * 1024;
  const char* ApB = (const char*)Ap + (size_t)nb * 256 * 1024;

  // fcol preload first: oldest vmem, drained by prologue vmcnt(0)
  float fcol[4];
  #pragma unroll
  for (int fc = 0; fc < 4; ++fc)
    fcol[fc] = frow[nb * 256 + wc * 64 + fc * 16 + l15];

  // per-lane x row base pointers (16B granules, B-fragment layout direct)
  const char* xrb[4];
  #pragma unroll
  for (int j = 0; j < 4; ++j)
    xrb[j] = ApB + (size_t)(wc * 64 + j * 16 + l15) * 1024 + lg * 16;

  // stage codes chunk cc into buf: ch 16KB @+0, cl 16KB @+16384 (4 gloads)
  auto STC = [&](int cc, char* buf) {
    #pragma unroll
    for (int rnd = 0; rnd < 2; ++rnd) {
      const size_t ro = (size_t)(rnd * 128 + rl0) * 1024 + (size_t)cc * 64 + srcS;
      gload_lds16(BpB + ro,       buf + rnd * 8192 + w * 1024);
      gload_lds16(BpB + ro + 512, buf + 16384 + rnd * 8192 + w * 1024);
    }
  };
  // load x chunk cc into register set (8 dwordx4, per-lane, L2-hit)
  auto LDX = [&](int cc, bf16x8* XH, bf16x8* XL) {
    #pragma unroll
    for (int j = 0; j < 4; ++j) {
      XH[j] = *reinterpret_cast<const bf16x8*>(xrb[j] + (size_t)cc * 64);
      XL[j] = *reinterpret_cast<const bf16x8*>(xrb[j] + (size_t)cc * 64 + 512);
    }
  };

  const int koX = (lg * 16) ^ ((l15 & 6) << 3);
  int aOff[8];
  #pragma unroll
  for (int fr = 0; fr < 8; ++fr) aOff[fr] = (wr * 128 + fr * 16 + l15) * 64;   // codes

  f32x4 acc[8][4];
  #pragma unroll
  for (int fr = 0; fr < 8; ++fr)
    #pragma unroll
    for (int fc = 0; fc < 4; ++fc) acc[fr][fc] = (f32x4){0.f, 0.f, 0.f, 0.f};

#define MM4(A0, av, bv)                                                       \
  __builtin_amdgcn_s_setprio(1);                                              \
  _Pragma("unroll")                                                           \
  for (int i_ = 0; i_ < 4; ++i_)                                              \
    _Pragma("unroll")                                                         \
    for (int j_ = 0; j_ < 4; ++j_)                                            \
      acc[(A0) + i_][j_] = __builtin_amdgcn_mfma_f32_16x16x32_bf16(           \
          (av)[i_], (bv)[j_], acc[(A0) + i_][j_], 0, 0, 0);                   \
  __builtin_amdgcn_s_setprio(0);

  // chunk body: prefetch batch {stage c+1, x c+1} -> vmcnt(12) publishes c
  auto BODY = [&](int c, bf16x8* XHc, bf16x8* XLc, bf16x8* XHn, bf16x8* XLn,
                  char* CURB, char* NXTB, bool pref) {
    if (pref) {
      __builtin_amdgcn_sched_barrier(0);
      STC(c + 1, NXTB);
      LDX(c + 1, XHn, XLn);
      __builtin_amdgcn_sched_barrier(0);
      asm volatile("s_waitcnt vmcnt(12)" ::: "memory");   // batch c drained
    } else {
      asm volatile("s_waitcnt vmcnt(0)" ::: "memory");
    }
    __builtin_amdgcn_s_barrier();                         // codes(c) published

    bf16x8 ch[8], cl[4];
    #pragma unroll
    for (int i = 0; i < 8; ++i)
      ch[i] = *reinterpret_cast<const bf16x8*>(CURB + aOff[i] + koX);
    MM4(0, ch,     XHc);                  // ch_h0 x xh
    MM4(4, ch + 4, XHc);                  // ch_h1 x xh

    #pragma unroll
    for (int i = 0; i < 4; ++i)
      cl[i] = *reinterpret_cast<const bf16x8*>(CURB + aOff[i] + 16384 + koX);
    MM4(0, cl, XHc);                      // cl_h0 x xh
    #pragma unroll
    for (int i = 0; i < 4; ++i)
      cl[i] = *reinterpret_cast<const bf16x8*>(CURB + aOff[4 + i] + 16384 + koX);
    MM4(4, cl, XHc);                      // cl_h1 x xh

    MM4(0, ch,     XLc);                  // ch_h0 x xl
    MM4(4, ch + 4, XLc);                  // ch_h1 x xl

    asm volatile("s_waitcnt lgkmcnt(0)" ::: "memory");    // my LDS reads retired
    __builtin_amdgcn_sched_barrier(0);
    __builtin_amdgcn_s_barrier();                         // CURB safe to overwrite
  };

  bf16x8 xhA[4], xlA[4], xhB[4], xlB[4];
  char* b0 = lds;
  char* b1 = lds + 32768;

  // prologue: chunk 0 -> b0 + x(0) -> set A
  STC(0, b0);
  LDX(0, xhA, xlA);
  asm volatile("s_waitcnt vmcnt(0)" ::: "memory");
  __builtin_amdgcn_s_barrier();

  for (int cp = 0; cp < 4; ++cp) {
    const int c0 = cp * 2;
    BODY(c0,     xhA, xlA, xhB, xlB, b0, b1, true);
    BODY(c0 + 1, xhB, xlB, xhA, xlA, b1, b0, cp < 3);
  }
#undef MM4

  // ---- epilogue: dist -> packed u64 key -> fold -> atomicMin per x-row ----
  // C layout: row(code_l) = wr*128 + fr*16 + lg*4 + rg ; col(x_l) = wc*64 + fc*16 + l15
  u64t bk[4] = {~0ull, ~0ull, ~0ull, ~0ull};
  #pragma unroll
  for (int fr = 0; fr < 8; ++fr) {
    const int cbase = cb * 256 + wr * 128 + fr * 16 + lg * 4;
    float4 en4 = *reinterpret_cast<const float4*>(enorm + cbase);
    const float en[4] = {en4.x, en4.y, en4.z, en4.w};
    #pragma unroll
    for (int fc = 0; fc < 4; ++fc)
      #pragma unroll
      for (int rg = 0; rg < 4; ++rg) {
        const float dist = (fcol[fc] + en[rg]) - 2.0f * acc[fr][fc][rg];
        const u64t key = ((u64t)__builtin_bit_cast(u32t, dist) << 32) | (u32t)(cbase + rg);
        if (key < bk[fc]) bk[fc] = key;
      }
  }
  #pragma unroll
  for (int off = 16; off <= 32; off <<= 1)
    #pragma unroll
    for (int fc = 0; fc < 4; ++fc) {
      const u64t o = shfl_xor_u64(bk[fc], off);
      if (o < bk[fc]) bk[fc] = o;
    }
  if (lg == 0) {
    #pragma unroll
    for (int fc = 0; fc < 4; ++fc)
      atomicMin(&keyArr[nb * 256 + wc * 64 + fc * 16 + l15], bk[fc]);
  }
}

// --- gather: key -> code -> out write + loss partial ---
__global__ __launch_bounds__(256) void vq_gather(const u64t* __restrict__ keyArr,
                                                 const float* __restrict__ Etg,
                                                 const float* __restrict__ x,
                                                 float* __restrict__ out,
                                                 float* __restrict__ partial) {
  __shared__ int codes[128];
  __shared__ float lpart[4];
  const int t  = threadIdx.x;
  const int r0 = blockIdx.x * 128;
  if (t < 128) codes[t] = (int)(u32t)keyArr[r0 + t];
  __syncthreads();
  float lsum = 0.f;
  for (int rr = 0; rr < 128; ++rr) {
    const int row  = r0 + rr;
    const int code = codes[rr];
    const float q  = Etg[(size_t)code * DDIM + t];
    const float xv = x[(size_t)row * DDIM + t];
    out[(size_t)row * DDIM + t] = q;
    const float df = q - xv;
    lsum += df * df;
  }
  #pragma unroll
  for (int off = 32; off; off >>= 1) lsum += __shfl_xor(lsum, off);
  if ((t & 63) == 0) lpart[t >> 6] = lsum;
  __syncthreads();
  if (t == 0) partial[blockIdx.x] = (lpart[0] + lpart[1]) + (lpart[2] + lpart[3]);
}

// --- final deterministic loss reduction ---
__global__ __launch_bounds__(256) void vq_final(const float* __restrict__ partial,
                                                float* __restrict__ loss_out) {
  double s = 0.0;
  for (int i = threadIdx.x; i < 512; i += 256) s += (double)partial[i];
  #pragma unroll
  for (int off = 32; off; off >>= 1) s += __shfl_xor(s, off);
  __shared__ double sh[4];
  if ((threadIdx.x & 63) == 0) sh[threadIdx.x >> 6] = s;
  __syncthreads();
  if (threadIdx.x == 0) {
    const double mean = (sh[0] + sh[1] + sh[2] + sh[3]) / 16777216.0;
    loss_out[0] = (float)(0.25 * mean - mean);
  }
}

extern "C" void kernel_launch(void* const* d_in, const int* in_sizes, int n_in,
                              void* d_out, int out_size, void* d_ws, size_t ws_size,
                              hipStream_t stream) {
  const float* x = (const float*)d_in[0];   // [65536, 256]
  const float* E = (const float*)d_in[1];   // [256, 2048]
  float* out = (float*)d_out;
  char*  ws  = (char*)d_ws;

  // ws layout (bytes): keyArr 512K | enorm 8K | frow 256K | partial 2K | Etg 2M | Bp 2M (~4.8 MB)
  u64t*  keyArr  = (u64t*)ws;
  float* enorm   = (float*)(ws + 524288);
  float* frow    = (float*)(ws + 524288 + 8192);
  float* partial = (float*)(ws + 524288 + 8192 + 262144);
  float* Etg     = (float*)(ws + 524288 + 8192 + 262144 + 2048);
  unsigned short* Bp = (unsigned short*)(ws + 524288 + 8192 + 262144 + 2048 + 2097152);

  unsigned short* Ap = (unsigned short*)d_out;   // A' overlay on out (consumed before gather writes)

  hipFuncSetAttribute(reinterpret_cast<const void*>(vq_nn),
                      hipFuncAttributeMaxDynamicSharedMemorySize, 65536);

  prep_A  <<<NROWS / 8, 256, 0, stream>>>(x, Ap, frow, keyArr);
  prep_B  <<<KCODE,     256, 0, stream>>>(E, Bp, enorm, Etg);
  vq_nn   <<<2048,      512, 65536, stream>>>(Ap, Bp, enorm, frow, keyArr);
  vq_gather<<<512,      256, 0, stream>>>(keyArr, Etg, x, out, partial);
  vq_final<<<1,         256, 0, stream>>>(partial, out + (size_t)NROWS * DDIM);
}

// Round 11
// 253.679 us; speedup vs baseline: 13.6472x; 13.6472x over previous
//
#include <hip/hip_runtime.h>

typedef __attribute__((ext_vector_type(8))) short bf16x8;
typedef __attribute__((ext_vector_type(4))) float f32x4;
typedef __attribute__((ext_vector_type(8))) unsigned short u16x8;
typedef unsigned long long u64t;
typedef unsigned int u32t;

#define NROWS 65536
#define DDIM  256
#define KCODE 2048

__device__ __forceinline__ unsigned short f2bf_rne(float f) {
  unsigned int u = __builtin_bit_cast(unsigned int, f);
  unsigned int r = (u + 0x7fffu + ((u >> 16) & 1u)) >> 16;
  return (unsigned short)r;
}
__device__ __forceinline__ float bf2f(unsigned short h) {
  unsigned int u = ((unsigned int)h) << 16;
  return __builtin_bit_cast(float, u);
}

typedef const unsigned int __attribute__((address_space(1)))* gp1_t;
typedef unsigned int __attribute__((address_space(3)))* lp3_t;
__device__ __forceinline__ void gload_lds16(const void* g, void* l) {
  __builtin_amdgcn_global_load_lds((gp1_t)g, (lp3_t)l, 16, 0, 0);
}

__device__ __forceinline__ u64t shfl_xor_u64(u64t v, int off) {
  u32t lo = (u32t)v, hi = (u32t)(v >> 32);
  lo = __shfl_xor(lo, off);
  hi = __shfl_xor(hi, off);
  return ((u64t)hi << 32) | lo;
}

// --- prep A: x -> [hi(256)|lo(256)] bf16 per row (overlay on d_out) + ||x||^2 + key init ---
__global__ __launch_bounds__(256) void prep_A(const float* __restrict__ x,
                                              unsigned short* __restrict__ Ap,
                                              float* __restrict__ frow,
                                              u64t* __restrict__ keyArr) {
  const int t   = threadIdx.x;
  const int row = blockIdx.x * 8 + (t >> 5);
  const int d0  = (t & 31) * 8;
  const float* xr = x + (size_t)row * DDIM + d0;
  float4 v0 = *reinterpret_cast<const float4*>(xr);
  float4 v1 = *reinterpret_cast<const float4*>(xr + 4);
  float vv[8] = {v0.x, v0.y, v0.z, v0.w, v1.x, v1.y, v1.z, v1.w};
  u16x8 hi, lo;
  float ss = 0.f;
  #pragma unroll
  for (int i = 0; i < 8; ++i) {
    ss += vv[i] * vv[i];
    unsigned short h = f2bf_rne(vv[i]);
    hi[i] = h;
    lo[i] = f2bf_rne(vv[i] - bf2f(h));
  }
  char* rowp = (char*)Ap + (size_t)row * 1024;
  *reinterpret_cast<u16x8*>(rowp + d0 * 2)       = hi;
  *reinterpret_cast<u16x8*>(rowp + 512 + d0 * 2) = lo;
  #pragma unroll
  for (int off = 16; off; off >>= 1) ss += __shfl_xor(ss, off);
  if ((t & 31) == 0) { frow[row] = ss; keyArr[row] = ~0ull; }
}

// --- prep B: E[d][k] -> Bp[k][512]=[hi(256)|lo(256)] bf16 k-major; enorm; Etg[k][d] fp32 ---
__global__ __launch_bounds__(256) void prep_B(const float* __restrict__ E,
                                              unsigned short* __restrict__ Bp,
                                              float* __restrict__ enorm,
                                              float* __restrict__ Etg) {
  const int k0 = blockIdx.x;
  const int d  = threadIdx.x;
  float v = E[(size_t)d * KCODE + k0];
  Etg[(size_t)k0 * DDIM + d] = v;
  unsigned short h = f2bf_rne(v);
  unsigned short l = f2bf_rne(v - bf2f(h));
  unsigned short* col = Bp + (size_t)k0 * 512;
  col[d] = h; col[256 + d] = l;
  float s = v * v;
  #pragma unroll
  for (int off = 32; off; off >>= 1) s += __shfl_xor(s, off);
  __shared__ float wsum[4];
  if ((threadIdx.x & 63) == 0) wsum[threadIdx.x >> 6] = s;
  __syncthreads();
  if (threadIdx.x == 0) enorm[k0] = (wsum[0] + wsum[1]) + (wsum[2] + wsum[3]);
}

// --- main: distance GEMM; SMALL independent blocks for cross-block pipe overlap.
// 256 threads (4 waves), tile 128 codes x 128 x. Codes in LDS (16KB/chunk,
// dbuf 32KB); x per-lane in named double-buffered registers. acc[8][2]=64 regs
// -> 2-3 blocks/CU co-resident with INDEPENDENT barriers: one block's MFMA
// covers another's read/barrier window. r9 chunk body otherwise unchanged.
__global__ __launch_bounds__(256, 2) void vq_nn(
    const unsigned short* __restrict__ Ap,   // x packed  [row][hi|lo] 1024 B/row
    const unsigned short* __restrict__ Bp,   // codes     [k][hi|lo]   1024 B/code
    const float* __restrict__ enorm,
    const float* __restrict__ frow,
    u64t* __restrict__ keyArr)
{
  extern __shared__ __align__(16) char lds[];   // 2 x { ch 8K | cl 8K } = 32 KB

  const int tid = threadIdx.x;
  const int w   = tid >> 6;      // wave 0..3 = x-col quarter
  const int l   = tid & 63;
  const int l15 = l & 15;
  const int lg  = l >> 4;

  // XCD swizzle: xcd owns contiguous nb range; consecutive seq sweeps cb
  // for the same nb slab -> x slab (128KB) L2-hot across 16 blocks.
  const int xcd = blockIdx.x & 7;
  const int s   = blockIdx.x >> 3;          // 0..1023
  const int cb  = s & 15;                   // code block 0..15 (128 codes)
  const int nb  = xcd * 64 + (s >> 4);      // x-row block 0..511 (128 rows)

  const int rl0  = tid >> 2;                // 0..63 (row within staging round)
  const int c16  = (tid & 3) * 16;
  const int srcS = c16 ^ (((rl0 >> 1) & 3) << 4);   // pre-swizzled source (involution)
  const char* BpB = (const char*)Bp + (size_t)cb * 128 * 1024;
  const char* ApB = (const char*)Ap + (size_t)nb * 128 * 1024;

  // fcol preload first (oldest vmem; drained by prologue vmcnt(0))
  float fcol0 = frow[nb * 128 + w * 32 +      l15];
  float fcol1 = frow[nb * 128 + w * 32 + 16 + l15];

  // per-lane x row pointers (B-fragment layout direct)
  const char* xp0 = ApB + (size_t)(w * 32 +      l15) * 1024 + lg * 16;
  const char* xp1 = ApB + (size_t)(w * 32 + 16 + l15) * 1024 + lg * 16;

  // stage codes chunk cc: ch 8KB @+0, cl 8KB @+8192 (4 gloads, 2 rounds of 64 rows)
  auto STC = [&](int cc, char* buf) {
    #pragma unroll
    for (int rnd = 0; rnd < 2; ++rnd) {
      const size_t ro = (size_t)(rnd * 64 + rl0) * 1024 + (size_t)cc * 64 + srcS;
      gload_lds16(BpB + ro,       buf + rnd * 4096 + w * 1024);
      gload_lds16(BpB + ro + 512, buf + 8192 + rnd * 4096 + w * 1024);
    }
  };

  const int koX = (lg * 16) ^ ((l15 & 6) << 3);
  int aOff[8];
  #pragma unroll
  for (int fr = 0; fr < 8; ++fr) aOff[fr] = (fr * 16 + l15) * 64;   // 128 code rows

  f32x4 acc[8][2];
  #pragma unroll
  for (int fr = 0; fr < 8; ++fr) {
    acc[fr][0] = (f32x4){0.f, 0.f, 0.f, 0.f};
    acc[fr][1] = (f32x4){0.f, 0.f, 0.f, 0.f};
  }

#define MM8(av, B0, B1)                                                       \
  __builtin_amdgcn_s_setprio(1);                                              \
  _Pragma("unroll")                                                           \
  for (int i_ = 0; i_ < 8; ++i_) {                                            \
    acc[i_][0] = __builtin_amdgcn_mfma_f32_16x16x32_bf16((av)[i_], (B0), acc[i_][0], 0, 0, 0); \
    acc[i_][1] = __builtin_amdgcn_mfma_f32_16x16x32_bf16((av)[i_], (B1), acc[i_][1], 0, 0, 0); \
  }                                                                           \
  __builtin_amdgcn_s_setprio(0);

// one chunk: prefetch batch {4 stage + 4 x-loads} -> vmcnt(8) publishes chunk c
#define CHUNK(c, CUR, NXT, XH0c, XH1c, XL0c, XL1c, XH0n, XH1n, XL0n, XL1n, PREF) \
  if (PREF) {                                                                 \
    STC((c) + 1, NXT);                                                       \
    XH0n = *(const bf16x8*)(xp0 + ((c) + 1) * 64);                           \
    XH1n = *(const bf16x8*)(xp1 + ((c) + 1) * 64);                           \
    XL0n = *(const bf16x8*)(xp0 + ((c) + 1) * 64 + 512);                     \
    XL1n = *(const bf16x8*)(xp1 + ((c) + 1) * 64 + 512);                     \
    asm volatile("s_waitcnt vmcnt(8)" ::: "memory");                         \
  } else {                                                                   \
    asm volatile("s_waitcnt vmcnt(0)" ::: "memory");                         \
  }                                                                          \
  __builtin_amdgcn_s_barrier();                                              \
  {                                                                          \
    bf16x8 ch[8], cl[8];                                                     \
    _Pragma("unroll")                                                        \
    for (int i_ = 0; i_ < 8; ++i_)                                           \
      ch[i_] = *(const bf16x8*)((CUR) + aOff[i_] + koX);                     \
    MM8(ch, XH0c, XH1c);                                                     \
    _Pragma("unroll")                                                        \
    for (int i_ = 0; i_ < 8; ++i_)                                           \
      cl[i_] = *(const bf16x8*)((CUR) + 8192 + aOff[i_] + koX);              \
    MM8(cl, XH0c, XH1c);                                                     \
    MM8(ch, XL0c, XL1c);                                                     \
  }                                                                          \
  asm volatile("s_waitcnt lgkmcnt(0)" ::: "memory");                         \
  __builtin_amdgcn_sched_barrier(0);                                         \
  __builtin_amdgcn_s_barrier();

  char* b0 = lds;
  char* b1 = lds + 16384;
  bf16x8 xhA0, xhA1, xlA0, xlA1, xhB0, xhB1, xlB0, xlB1;

  // prologue: chunk 0 -> b0 + x(0) -> set A
  STC(0, b0);
  xhA0 = *(const bf16x8*)(xp0);
  xhA1 = *(const bf16x8*)(xp1);
  xlA0 = *(const bf16x8*)(xp0 + 512);
  xlA1 = *(const bf16x8*)(xp1 + 512);
  asm volatile("s_waitcnt vmcnt(0)" ::: "memory");
  __builtin_amdgcn_s_barrier();

  for (int cp = 0; cp < 4; ++cp) {
    const int c0 = cp * 2;
    CHUNK(c0,     b0, b1, xhA0, xhA1, xlA0, xlA1, xhB0, xhB1, xlB0, xlB1, true)
    CHUNK(c0 + 1, b1, b0, xhB0, xhB1, xlB0, xlB1, xhA0, xhA1, xlA0, xlA1, (cp < 3))
  }
#undef CHUNK
#undef MM8

  // ---- epilogue: dist -> packed u64 key -> fold -> atomicMin per x-row ----
  // C layout: row(code) = fr*16 + lg*4 + rg ; col(x) = w*32 + fc*16 + l15
  u64t bk0 = ~0ull, bk1 = ~0ull;
  #pragma unroll
  for (int fr = 0; fr < 8; ++fr) {
    const int cbase = cb * 128 + fr * 16 + lg * 4;
    float4 en4 = *reinterpret_cast<const float4*>(enorm + cbase);
    const float en[4] = {en4.x, en4.y, en4.z, en4.w};
    #pragma unroll
    for (int rg = 0; rg < 4; ++rg) {
      const float d0 = (fcol0 + en[rg]) - 2.0f * acc[fr][0][rg];
      const float d1 = (fcol1 + en[rg]) - 2.0f * acc[fr][1][rg];
      const u64t k0 = ((u64t)__builtin_bit_cast(u32t, d0) << 32) | (u32t)(cbase + rg);
      const u64t k1 = ((u64t)__builtin_bit_cast(u32t, d1) << 32) | (u32t)(cbase + rg);
      if (k0 < bk0) bk0 = k0;
      if (k1 < bk1) bk1 = k1;
    }
  }
  #pragma unroll
  for (int off = 16; off <= 32; off <<= 1) {
    const u64t o0 = shfl_xor_u64(bk0, off);
    const u64t o1 = shfl_xor_u64(bk1, off);
    if (o0 < bk0) bk0 = o0;
    if (o1 < bk1) bk1 = o1;
  }
  if (lg == 0) {
    atomicMin(&keyArr[nb * 128 + w * 32 +      l15], bk0);
    atomicMin(&keyArr[nb * 128 + w * 32 + 16 + l15], bk1);
  }
}

// --- gather: key -> code -> out write + loss partial ---
__global__ __launch_bounds__(256) void vq_gather(const u64t* __restrict__ keyArr,
                                                 const float* __restrict__ Etg,
                                                 const float* __restrict__ x,
                                                 float* __restrict__ out,
                                                 float* __restrict__ partial) {
  __shared__ int codes[128];
  __shared__ float lpart[4];
  const int t  = threadIdx.x;
  const int r0 = blockIdx.x * 128;
  if (t < 128) codes[t] = (int)(u32t)keyArr[r0 + t];
  __syncthreads();
  float lsum = 0.f;
  for (int rr = 0; rr < 128; ++rr) {
    const int row  = r0 + rr;
    const int code = codes[rr];
    const float q  = Etg[(size_t)code * DDIM + t];
    const float xv = x[(size_t)row * DDIM + t];
    out[(size_t)row * DDIM + t] = q;
    const float df = q - xv;
    lsum += df * df;
  }
  #pragma unroll
  for (int off = 32; off; off >>= 1) lsum += __shfl_xor(lsum, off);
  if ((t & 63) == 0) lpart[t >> 6] = lsum;
  __syncthreads();
  if (t == 0) partial[blockIdx.x] = (lpart[0] + lpart[1]) + (lpart[2] + lpart[3]);
}

// --- final deterministic loss reduction ---
__global__ __launch_bounds__(256) void vq_final(const float* __restrict__ partial,
                                                float* __restrict__ loss_out) {
  double s = 0.0;
  for (int i = threadIdx.x; i < 512; i += 256) s += (double)partial[i];
  #pragma unroll
  for (int off = 32; off; off >>= 1) s += __shfl_xor(s, off);
  __shared__ double sh[4];
  if ((threadIdx.x & 63) == 0) sh[threadIdx.x >> 6] = s;
  __syncthreads();
  if (threadIdx.x == 0) {
    const double mean = (sh[0] + sh[1] + sh[2] + sh[3]) / 16777216.0;
    loss_out[0] = (float)(0.25 * mean - mean);
  }
}

extern "C" void kernel_launch(void* const* d_in, const int* in_sizes, int n_in,
                              void* d_out, int out_size, void* d_ws, size_t ws_size,
                              hipStream_t stream) {
  const float* x = (const float*)d_in[0];   // [65536, 256]
  const float* E = (const float*)d_in[1];   // [256, 2048]
  float* out = (float*)d_out;
  char*  ws  = (char*)d_ws;

  // ws layout (bytes): keyArr 512K | enorm 8K | frow 256K | partial 2K | Etg 2M | Bp 2M (~4.8 MB)
  u64t*  keyArr  = (u64t*)ws;
  float* enorm   = (float*)(ws + 524288);
  float* frow    = (float*)(ws + 524288 + 8192);
  float* partial = (float*)(ws + 524288 + 8192 + 262144);
  float* Etg     = (float*)(ws + 524288 + 8192 + 262144 + 2048);
  unsigned short* Bp = (unsigned short*)(ws + 524288 + 8192 + 262144 + 2048 + 2097152);

  unsigned short* Ap = (unsigned short*)d_out;   // A' overlay on out (consumed before gather writes)

  hipFuncSetAttribute(reinterpret_cast<const void*>(vq_nn),
                      hipFuncAttributeMaxDynamicSharedMemorySize, 32768);

  prep_A  <<<NROWS / 8, 256, 0, stream>>>(x, Ap, frow, keyArr);
  prep_B  <<<KCODE,     256, 0, stream>>>(E, Bp, enorm, Etg);
  vq_nn   <<<8192,      256, 32768, stream>>>(Ap, Bp, enorm, frow, keyArr);
  vq_gather<<<512,      256, 0, stream>>>(keyArr, Etg, x, out, partial);
  vq_final<<<1,         256, 0, stream>>>(partial, out + (size_t)NROWS * DDIM);
}